// Round 6
// baseline (359.216 us; speedup 1.0000x reference)
//
#include <hip/hip_runtime.h>

#define LIMG 4
#define CIN 256
#define HH 128
#define WW 256
#define HW 32768          // HH*WW
#define LHW 131072        // LIMG*HW
#define CD 128
#define KP 256
#define CAP 8192
#define NSP 2
#define CPER (CIN/NSP)    // 128
#define NINF -3.402823466e38f

// ---------------- fused: channel-reduced score planes + weight transpose + cnt ----------------
// blocks [0,1024): chanred ; blocks [1024, 1024+1152): wtrans (+cnt init)
__global__ __launch_bounds__(256) void k_chanred(const float* __restrict__ feats,
                                                 const float* __restrict__ wS,
                                                 float* __restrict__ g,
                                                 const float* __restrict__ wD,
                                                 float* __restrict__ wT,
                                                 int* __restrict__ cnt) {
  int bid = blockIdx.x;
  if (bid >= 1024) {
    int i = (bid - 1024) * 256 + threadIdx.x;
    if (i < LIMG) cnt[i] = 0;
    if (i < CD * CIN * 9) {
      int d = i & (CD - 1);
      int j = i >> 7;                    // c*9+tap
      wT[i] = wD[d * (CIN * 9) + j];
    }
    return;
  }
  int gp   = (bid & 511) * 256 + threadIdx.x;  // 0..131071
  int half = bid >> 9;                         // 0..NSP-1
  int l  = gp >> 15;
  int pi = gp & (HW - 1);
  const float* f = feats + (size_t)(l * CIN + half * CPER) * HW + pi;
  const float* w = wS + half * CPER * 9;
  float a0=0,a1=0,a2=0,a3=0,a4=0,a5=0,a6=0,a7=0,a8=0;
  #pragma unroll 4
  for (int c = 0; c < CPER; ++c) {
    float v = f[(size_t)c * HW];
    const float* wc = w + c * 9;
    a0 = fmaf(wc[0], v, a0); a1 = fmaf(wc[1], v, a1); a2 = fmaf(wc[2], v, a2);
    a3 = fmaf(wc[3], v, a3); a4 = fmaf(wc[4], v, a4); a5 = fmaf(wc[5], v, a5);
    a6 = fmaf(wc[6], v, a6); a7 = fmaf(wc[7], v, a7); a8 = fmaf(wc[8], v, a8);
  }
  float* go = g + (size_t)(half * 9) * LHW + gp;
  go[0*(size_t)LHW]=a0; go[1*(size_t)LHW]=a1; go[2*(size_t)LHW]=a2;
  go[3*(size_t)LHW]=a3; go[4*(size_t)LHW]=a4; go[5*(size_t)LHW]=a5;
  go[6*(size_t)LHW]=a6; go[7*(size_t)LHW]=a7; go[8*(size_t)LHW]=a8;
}

// ---------------- fused: scores (from g) + NMS stage0 + NMS iteration 1 ----------------
// grid: 4 img x 16 ytiles = 64 blocks, 256 threads (one per column).
// computes scores rows [y0-12, y0+20) locally, writes center 8 score rows to
// global, then mask0 (halo 8) and one supp/newmax iteration; writes mask rows
// [y0, y0+8). pad-0 for mask/supp pools == reference pad(-inf): windows at
// valid centers always contain their own >=0 center value.
__global__ __launch_bounds__(256) void k_nmsA(const float* __restrict__ g,
                                              const float* __restrict__ bS,
                                              float* __restrict__ scores,
                                              float* __restrict__ maskout) {
  __shared__ float sS[32][WW];   // scores rows y0-12 .. y0+19
  __shared__ float sR[32][WW];   // scratch rowmax
  __shared__ float sM[24][WW];   // mask0 rows y0-8 .. y0+15
  __shared__ float ss[16][WW];   // supp_scores rows y0-4 .. y0+11
  __shared__ float rs[16][WW];   // rowmax of ss
  int b = blockIdx.x;
  int l = b >> 4;
  int y0 = (b & 15) * 8;
  int x = threadIdx.x;
  float bias = bS[0];
  for (int r = 0; r < 32; ++r) {
    int y = y0 - 12 + r;
    float v = NINF;
    if (y >= 0 && y < HH) {
      float acc = bias;
      #pragma unroll
      for (int ky = 0; ky < 3; ++ky) {
        int yy = y + ky - 1;
        if (yy < 0 || yy >= HH) continue;
        #pragma unroll
        for (int kx = 0; kx < 3; ++kx) {
          int xx = x + kx - 1;
          if (xx < 0 || xx >= WW) continue;
          int tap = ky * 3 + kx;
          size_t qof = (size_t)l * HW + yy * WW + xx;
          acc += g[(size_t)tap * LHW + qof] + g[(size_t)(9 + tap) * LHW + qof];
        }
      }
      v = 1.0f / (1.0f + expf(-acc));
      if (y >= y0 && y < y0 + 8) scores[l * HW + y * WW + x] = v;
    }
    sS[r][x] = v;
  }
  __syncthreads();
  for (int r = 0; r < 32; ++r) {
    float m = NINF;
    #pragma unroll
    for (int dx = -4; dx <= 4; ++dx) {
      int xx = x + dx;
      if (xx >= 0 && xx < WW) m = fmaxf(m, sS[r][xx]);
    }
    sR[r][x] = m;
  }
  __syncthreads();
  for (int r = 0; r < 24; ++r) {
    int y = y0 - 8 + r;
    float m = NINF;
    #pragma unroll
    for (int t = 0; t < 9; ++t) m = fmaxf(m, sR[r + t][x]);
    sM[r][x] = (y >= 0 && y < HH && sS[r + 4][x] == m) ? 1.0f : 0.0f;
  }
  __syncthreads();
  for (int r = 0; r < 24; ++r) {
    float m = 0.0f;
    #pragma unroll
    for (int dx = -4; dx <= 4; ++dx) {
      int xx = x + dx;
      if (xx >= 0 && xx < WW) m = fmaxf(m, sM[r][xx]);
    }
    sR[r][x] = m;
  }
  __syncthreads();
  float smcreg[8];
  for (int r2 = 0; r2 < 16; ++r2) {
    float m = 0.0f;
    #pragma unroll
    for (int t = 0; t < 9; ++t) m = fmaxf(m, sR[r2 + t][x]);
    bool sm = m > 0.0f;
    int y = y0 - 4 + r2;
    float sv = (y >= 0 && y < HH) ? sS[r2 + 8][x] : 0.0f;
    ss[r2][x] = sm ? 0.0f : sv;
    if (r2 >= 4 && r2 < 12) smcreg[r2 - 4] = sm ? 1.0f : 0.0f;
  }
  __syncthreads();
  for (int r2 = 0; r2 < 16; ++r2) {
    float m = NINF;
    #pragma unroll
    for (int dx = -4; dx <= 4; ++dx) {
      int xx = x + dx;
      if (xx >= 0 && xx < WW) m = fmaxf(m, ss[r2][xx]);
    }
    rs[r2][x] = m;
  }
  __syncthreads();
  for (int r = 0; r < 8; ++r) {
    float m = NINF;
    #pragma unroll
    for (int t = 0; t < 9; ++t) m = fmaxf(m, rs[r + t][x]);
    bool nm = (ss[r + 4][x] == m) && (smcreg[r] == 0.0f);
    float prev = sM[r + 8][x];
    maskout[l * HW + (y0 + r) * WW + x] = (prev != 0.0f || nm) ? 1.0f : 0.0f;
  }
}

// ---------------- NMS iteration 2 (mask halo 8 from global) + candidate collect ----------------
#define PROWS 8
__global__ __launch_bounds__(256) void k_nmsB(const float* __restrict__ maskin,
                                              const float* __restrict__ scores,
                                              float* __restrict__ maskout,
                                              int* __restrict__ cnt,
                                              int* __restrict__ cidx,
                                              float* __restrict__ csc) {
  __shared__ float m24[PROWS + 16][WW];
  __shared__ float rm[PROWS + 16][WW];
  __shared__ float ss[PROWS + 8][WW];
  __shared__ float rs[PROWS + 8][WW];
  __shared__ float smc[PROWS][WW];
  int b = blockIdx.x;
  int l = b >> 4;
  int y0 = (b & 15) * PROWS;
  int x = threadIdx.x;
  const float* ml = maskin + (size_t)l * HW;
  const float* sl = scores + (size_t)l * HW;
  #pragma unroll
  for (int r = 0; r < PROWS + 16; ++r) {
    int yy = y0 - 8 + r;
    m24[r][x] = (yy >= 0 && yy < HH) ? ml[yy * WW + x] : 0.0f;
  }
  __syncthreads();
  #pragma unroll
  for (int r = 0; r < PROWS + 16; ++r) {
    float m = 0.0f;
    #pragma unroll
    for (int dx = -4; dx <= 4; ++dx) {
      int xx = x + dx;
      if (xx >= 0 && xx < WW) m = fmaxf(m, m24[r][xx]);
    }
    rm[r][x] = m;
  }
  __syncthreads();
  #pragma unroll
  for (int r2 = 0; r2 < PROWS + 8; ++r2) {
    float m = 0.0f;
    #pragma unroll
    for (int t = 0; t < 9; ++t) m = fmaxf(m, rm[r2 + t][x]);
    bool sm = m > 0.0f;
    int yy = y0 - 4 + r2;
    float sv = (yy >= 0 && yy < HH) ? sl[yy * WW + x] : 0.0f;
    ss[r2][x] = sm ? 0.0f : sv;
    if (r2 >= 4 && r2 < 4 + PROWS) smc[r2 - 4][x] = sm ? 1.0f : 0.0f;
  }
  __syncthreads();
  #pragma unroll
  for (int r2 = 0; r2 < PROWS + 8; ++r2) {
    float m = NINF;
    #pragma unroll
    for (int dx = -4; dx <= 4; ++dx) {
      int xx = x + dx;
      if (xx >= 0 && xx < WW) m = fmaxf(m, ss[r2][xx]);
    }
    rs[r2][x] = m;
  }
  __syncthreads();
  #pragma unroll
  for (int r = 0; r < PROWS; ++r) {
    float m = NINF;
    #pragma unroll
    for (int t = 0; t < 9; ++t) m = fmaxf(m, rs[r + t][x]);
    bool nm = (ss[r + 4][x] == m) && (smc[r][x] == 0.0f);
    float prev = m24[r + 8][x];
    float outv = (prev != 0.0f || nm) ? 1.0f : 0.0f;
    int p = (y0 + r) * WW + x;
    maskout[l * HW + p] = outv;
    if (outv != 0.0f) {
      int pos = atomicAdd(&cnt[l], 1);
      if (pos < CAP) {
        cidx[l * CAP + pos] = p;
        csc[l * CAP + pos]  = sl[p];
      }
    }
  }
}

// ---------------- rank-based stable top-k + zero-score fill ----------------
__global__ __launch_bounds__(256) void k_rankfill(const int* __restrict__ cnt,
                                                  const int* __restrict__ cidx,
                                                  const float* __restrict__ csc,
                                                  const float* __restrict__ mask,
                                                  int* __restrict__ sel) {
  __shared__ unsigned long long keys[CAP];   // 64 KiB
  __shared__ int csum[256];
  int b = blockIdx.x;            // 32 blocks: 8 per image
  int l = b >> 3;
  int tid = threadIdx.x;
  int M = cnt[l]; if (M > CAP) M = CAP;
  const int* ci = cidx + l * CAP;
  const float* cs = csc + l * CAP;
  for (int j = tid; j < M; j += 256) {
    unsigned int ks = __float_as_uint(cs[j]);   // scores > 0 -> bits monotone
    keys[j] = ((unsigned long long)(0xFFFFFFFFu - ks) << 32) | (unsigned int)ci[j];
  }
  __syncthreads();
  for (int i = (b & 7) * 256 + tid; i < M; i += 2048) {
    unsigned long long ki = keys[i];
    int rank = 0;
    for (int j = 0; j < M; ++j)
      rank += (keys[j] < ki) ? 1 : 0;
    if (rank < KP) sel[l * KP + rank] = (int)(unsigned int)(ki & 0xFFFFFFFFu);
  }
  if ((b & 7) != 0) return;
  int Mc = (M < KP) ? M : KP;
  int need = KP - Mc;
  if (need > 0) {
    const float* mk = mask + (size_t)l * HW;
    const int per = HW / 256;               // 128
    int base = tid * per;
    int c = 0;
    for (int q = 0; q < per; ++q) c += (mk[base + q] == 0.0f) ? 1 : 0;
    int inc = c;
    csum[tid] = c;
    __syncthreads();
    for (int s = 1; s < 256; s <<= 1) {
      int v = (tid >= s) ? csum[tid - s] : 0;
      __syncthreads();
      csum[tid] += v;
      __syncthreads();
    }
    int excl = csum[tid] - inc;
    if (excl < need) {
      int r = excl;
      for (int q = 0; q < per && r < need; ++q) {
        if (mk[base + q] == 0.0f) { sel[l * KP + Mc + r] = base + q; ++r; }
      }
    }
  }
}

// ---------------- desc conv phase 1: 32 kp / block, 8-way channel split ----------------
// grid: q(8) x kb(8) x l(4) = 256 blocks, 256 threads. pacc[q][l][k][d]
__global__ __launch_bounds__(256) void k_desc1(const float* __restrict__ feats,
                                               const float* __restrict__ wT,
                                               const int* __restrict__ sel,
                                               float* __restrict__ pacc) {
  __shared__ float patch[32][288];     // 36.9 KiB
  __shared__ int kpix[32];
  int b = blockIdx.x;
  int q  = b & 7;
  int kb = (b >> 3) & 7;
  int l  = b >> 6;
  int k0 = kb * 32;
  int tid = threadIdx.x;
  if (tid < 32) kpix[tid] = sel[l * KP + k0 + tid];
  __syncthreads();
  int c0 = q * 32;
  for (int e = tid; e < 32 * 288; e += 256) {
    int kp = e / 288;
    int j  = e - kp * 288;
    int c  = j / 9;
    int tap = j - c * 9;
    int ky = tap / 3, kx = tap - ky * 3;
    int pix = kpix[kp];
    int y = pix >> 8, x = pix & 255;
    int yy = y + ky - 1, xx = x + kx - 1;
    float v = 0.0f;
    if (yy >= 0 && yy < HH && xx >= 0 && xx < WW)
      v = feats[((size_t)(l * CIN + c0 + c) * HH + yy) * WW + xx];
    patch[kp][j] = v;
  }
  __syncthreads();
  int d = tid & 127;
  int gg = tid >> 7;                    // kp group of 16
  const float* w = wT + (size_t)(q * 288) * CD + d;
  float a[16];
  #pragma unroll
  for (int i = 0; i < 16; ++i) a[i] = 0.0f;
  #pragma unroll 2
  for (int j = 0; j < 288; j += 4) {
    float w0 = w[(size_t)(j + 0) * CD];
    float w1 = w[(size_t)(j + 1) * CD];
    float w2 = w[(size_t)(j + 2) * CD];
    float w3 = w[(size_t)(j + 3) * CD];
    #pragma unroll
    for (int i = 0; i < 16; ++i) {
      float4 qv = *(const float4*)&patch[16 * gg + i][j];
      a[i] = fmaf(w0, qv.x, a[i]);
      a[i] = fmaf(w1, qv.y, a[i]);
      a[i] = fmaf(w2, qv.z, a[i]);
      a[i] = fmaf(w3, qv.w, a[i]);
    }
  }
  size_t base = (((size_t)q * LIMG + l) * KP + k0 + 16 * gg) * CD + d;
  #pragma unroll
  for (int i = 0; i < 16; ++i)
    pacc[base + (size_t)i * CD] = a[i];
}

// ---------------- fused: combine 8 partials + bias + relu + L2 norm + attention ----------------
__global__ __launch_bounds__(128) void k_desc2attn(const float* __restrict__ pacc,
                                                   const float* __restrict__ bD,
                                                   float* __restrict__ d2) {
  __shared__ float ps[2][LIMG];
  __shared__ float qs[LIMG][CD];
  __shared__ float dm[16];
  int k = blockIdx.x;
  int d = threadIdx.x;
  float bv = bD[d];
  float r[LIMG];
  #pragma unroll
  for (int l = 0; l < LIMG; ++l) {
    float s = bv;
    #pragma unroll
    for (int qq = 0; qq < 8; ++qq)
      s += pacc[(((size_t)qq * LIMG + l) * KP + k) * CD + d];
    r[l] = fmaxf(s, 0.0f);
  }
  int lane = d & 63, wid = d >> 6;
  #pragma unroll
  for (int l = 0; l < LIMG; ++l) {
    float v = r[l] * r[l];
    #pragma unroll
    for (int sh = 32; sh > 0; sh >>= 1) v += __shfl_down(v, sh);
    if (lane == 0) ps[wid][l] = v;
  }
  __syncthreads();
  float q[LIMG];
  #pragma unroll
  for (int l = 0; l < LIMG; ++l) {
    float n = fmaxf(sqrtf(ps[0][l] + ps[1][l]), 1e-12f);
    q[l] = r[l] / n;
    qs[l][d] = q[l];
  }
  __syncthreads();
  if (d < 16) {
    int n = d >> 2, m = d & 3;
    float s = 0.f;
    for (int t = 0; t < CD; ++t) s = fmaf(qs[n][t], qs[m][t], s);
    dm[d] = s * 0.08838834764831843f;     // 1/sqrt(128)
  }
  __syncthreads();
  #pragma unroll
  for (int n = 0; n < LIMG; ++n) {
    float a0 = dm[n*4+0], a1 = dm[n*4+1], a2 = dm[n*4+2], a3 = dm[n*4+3];
    float mx = fmaxf(fmaxf(a0, a1), fmaxf(a2, a3));
    float e0 = expf(a0 - mx), e1 = expf(a1 - mx), e2 = expf(a2 - mx), e3 = expf(a3 - mx);
    float inv = 1.0f / (e0 + e1 + e2 + e3);
    float msg = (e0 * q[0] + e1 * q[1] + e2 * q[2] + e3 * q[3]) * inv;
    d2[(size_t)(n * CD + d) * KP + k] = 2.0f * q[n] + msg;
  }
}

// ---------------- conv1d k=3 pad=1 + relu ----------------
__global__ __launch_bounds__(256) void k_proj(const float* __restrict__ d2, const float* __restrict__ pw,
                                              const float* __restrict__ pb, float* __restrict__ d3) {
  int b = blockIdx.x;
  int l = b >> 7, o = b & 127;
  int k = threadIdx.x;
  float acc = pb[o];
  for (int c = 0; c < CD; ++c) {
    const float* row = d2 + (size_t)(l * CD + c) * KP;
    float xm = (k > 0)      ? row[k - 1] : 0.f;
    float x0 = row[k];
    float xp = (k < KP - 1) ? row[k + 1] : 0.f;
    const float* w = pw + (size_t)(o * CD + c) * 3;
    acc = fmaf(w[0], xm, acc);
    acc = fmaf(w[1], x0, acc);
    acc = fmaf(w[2], xp, acc);
  }
  d3[(size_t)(l * CD + o) * KP + k] = fmaxf(acc, 0.f);
}

// ---------------- fused: conv1d k=1 + stable descending argsort + gather ----------------
__global__ __launch_bounds__(256) void k_projsort(const float* __restrict__ d3,
                                                  const float* __restrict__ psw,
                                                  const float* __restrict__ psb,
                                                  float* __restrict__ d4) {
  int b = blockIdx.x;
  int l = b >> 7, o = b & 127;
  int k = threadIdx.x;
  __shared__ float srow[KP];
  float acc = psb[o];
  for (int c = 0; c < CD; ++c)
    acc = fmaf(psw[o * CD + c], d3[(size_t)(l * CD + c) * KP + k], acc);
  srow[k] = acc;
  __syncthreads();
  int rank = 0;
  for (int m = 0; m < KP; ++m) {
    float sm = srow[m];
    rank += (sm > acc || (sm == acc && m < k)) ? 1 : 0;
  }
  int base = (l * CD + o) * KP;
  d4[base + rank] = d3[base + k];
}

// ---------------- fused: final conv1d (128->3) + min|diff| -> theta ----------------
__global__ __launch_bounds__(1024) void k_finaltheta(const float* __restrict__ d4,
                                                     const float* __restrict__ fw,
                                                     const float* __restrict__ fb,
                                                     float* __restrict__ theta) {
  __shared__ float accs[LIMG][KP][3];
  __shared__ float res[LIMG][3];
  int tid = threadIdx.x;
  int l = tid >> 8, k = tid & 255;
  float a0 = fb[0], a1 = fb[1], a2 = fb[2];
  const float* dl = d4 + (size_t)l * CD * KP + k;
  for (int c = 0; c < CD; ++c) {
    float v = dl[(size_t)c * KP];
    a0 = fmaf(fw[0 * CD + c], v, a0);
    a1 = fmaf(fw[1 * CD + c], v, a1);
    a2 = fmaf(fw[2 * CD + c], v, a2);
  }
  accs[l][k][0] = a0; accs[l][k][1] = a1; accs[l][k][2] = a2;
  __syncthreads();
  int wid = tid >> 6, lane = tid & 63;
  if (wid < 12) {
    int rl = wid / 3, ro = wid - rl * 3;
    float m = 3.402823466e38f;
    #pragma unroll
    for (int t = 0; t < 4; ++t) {
      int kk = lane + 64 * t;
      m = fminf(m, fabsf(accs[rl][kk][ro] - accs[0][kk][ro]));
    }
    #pragma unroll
    for (int s = 32; s > 0; s >>= 1) m = fminf(m, __shfl_down(m, s));
    if (lane == 0) res[rl][ro] = m;
  }
  __syncthreads();
  if (tid == 0) {
    for (int l2 = 0; l2 < LIMG; ++l2) {
      float tx = res[l2][0], ty = res[l2][1], th = res[l2][2];
      float cth = cosf(th), sth = sinf(th);
      theta[l2*6+0] = cth;  theta[l2*6+1] = -sth; theta[l2*6+2] = tx;
      theta[l2*6+3] = sth;  theta[l2*6+4] = cth;  theta[l2*6+5] = ty;
    }
  }
}

// ---------------- bilinear grid sample: 8 channels per thread ----------------
__global__ __launch_bounds__(256) void k_sample(const float* __restrict__ feats,
                                                const float* __restrict__ theta,
                                                float* __restrict__ out) {
  int b = blockIdx.x;
  int pb = b & 127;
  int cg = (b >> 7) & 31;
  int l  = b >> 12;
  int pi = pb * 256 + threadIdx.x;
  int x = pi & 255, y = pi >> 8;
  const float* t = theta + l * 6;
  float X = (x + 0.5f) * (2.0f / WW) - 1.0f;
  float Y = (y + 0.5f) * (2.0f / HH) - 1.0f;
  float gx = t[0] * X + t[1] * Y + t[2];
  float gy = t[3] * X + t[4] * Y + t[5];
  float ix = ((gx + 1.0f) * WW - 1.0f) * 0.5f;
  float iy = ((gy + 1.0f) * HH - 1.0f) * 0.5f;
  float x0 = floorf(ix), y0 = floorf(iy);
  float x1 = x0 + 1.0f,  y1 = y0 + 1.0f;
  float wa = (x1 - ix) * (y1 - iy);
  float wb = (ix - x0) * (y1 - iy);
  float wc = (x1 - ix) * (iy - y0);
  float wd = (ix - x0) * (iy - y0);
  bool vx0 = (x0 >= 0.f) && (x0 <= (float)(WW-1));
  bool vx1 = (x1 >= 0.f) && (x1 <= (float)(WW-1));
  bool vy0 = (y0 >= 0.f) && (y0 <= (float)(HH-1));
  bool vy1 = (y1 >= 0.f) && (y1 <= (float)(HH-1));
  wa = (vx0 && vy0) ? wa : 0.f;
  wb = (vx1 && vy0) ? wb : 0.f;
  wc = (vx0 && vy1) ? wc : 0.f;
  wd = (vx1 && vy1) ? wd : 0.f;
  int xc0 = (int)fminf(fmaxf(x0, 0.f), (float)(WW-1));
  int xc1 = (int)fminf(fmaxf(x1, 0.f), (float)(WW-1));
  int yc0 = (int)fminf(fmaxf(y0, 0.f), (float)(HH-1));
  int yc1 = (int)fminf(fmaxf(y1, 0.f), (float)(HH-1));
  int o00 = yc0 * WW + xc0;
  int o10 = yc0 * WW + xc1;
  int o01 = yc1 * WW + xc0;
  int o11 = yc1 * WW + xc1;
  const float* img = feats + (size_t)(l * CIN + cg * 8) * HW;
  float* op = out + (size_t)(l * CIN + cg * 8) * HW + pi;
  #pragma unroll
  for (int i = 0; i < 8; ++i) {
    const float* im = img + (size_t)i * HW;
    float acc = im[o00] * wa + im[o10] * wb + im[o01] * wc + im[o11] * wd;
    op[(size_t)i * HW] = acc;
  }
}

extern "C" void kernel_launch(void* const* d_in, const int* in_sizes, int n_in,
                              void* d_out, int out_size, void* d_ws, size_t ws_size,
                              hipStream_t stream) {
  const float* feats = (const float*)d_in[0];
  const float* wS    = (const float*)d_in[1];
  const float* bS    = (const float*)d_in[2];
  const float* wD    = (const float*)d_in[3];
  const float* bD    = (const float*)d_in[4];
  const float* pw    = (const float*)d_in[5];
  const float* pb    = (const float*)d_in[6];
  const float* psw   = (const float*)d_in[7];
  const float* psb   = (const float*)d_in[8];
  const float* fw    = (const float*)d_in[9];
  const float* fb    = (const float*)d_in[10];
  float* out = (float*)d_out;

  char* base = (char*)d_ws;
  size_t off = 0;
  auto alloc = [&](size_t bytes) -> void* {
    void* p = base + off;
    off = (off + bytes + 255) & ~(size_t)255;
    return p;
  };
  float* g      = (float*)alloc((size_t)NSP * 9 * LHW * sizeof(float));
  float* scores = (float*)alloc((size_t)LHW * 4);
  float* maskA  = (float*)alloc((size_t)LHW * 4);
  float* maskB  = (float*)alloc((size_t)LHW * 4);
  float* d2     = (float*)alloc((size_t)LHW * 4);
  float* d3     = (float*)alloc((size_t)LHW * 4);
  float* d4     = (float*)alloc((size_t)LHW * 4);
  float* wT     = (float*)alloc((size_t)CIN * 9 * CD * 4);
  float* pacc   = (float*)alloc((size_t)8 * LIMG * KP * CD * 4);
  float* theta  = (float*)alloc(24 * 4);
  float* csc    = (float*)alloc((size_t)LIMG * CAP * 4);
  int*   cidx   = (int*)  alloc((size_t)LIMG * CAP * 4);
  int*   cnt    = (int*)  alloc(64);
  int*   sel    = (int*)  alloc((size_t)LIMG * KP * 4);

  const int WT_BLOCKS = (CD * CIN * 9 + 255) / 256;   // 1152
  k_chanred<<<1024 + WT_BLOCKS, 256, 0, stream>>>(feats, wS, g, wD, wT, cnt);
  k_nmsA<<<64, 256, 0, stream>>>(g, bS, scores, maskA);
  k_nmsB<<<64, 256, 0, stream>>>(maskA, scores, maskB, cnt, cidx, csc);
  k_rankfill<<<32, 256, 0, stream>>>(cnt, cidx, csc, maskB, sel);
  k_desc1<<<256, 256, 0, stream>>>(feats, wT, sel, pacc);
  k_desc2attn<<<256, 128, 0, stream>>>(pacc, bD, d2);
  k_proj<<<512, 256, 0, stream>>>(d2, pw, pb, d3);
  k_projsort<<<512, 256, 0, stream>>>(d3, psw, psb, d4);
  k_finaltheta<<<1, 1024, 0, stream>>>(d4, fw, fb, theta);
  k_sample<<<16384, 256, 0, stream>>>(feats, theta, out);
}

// Round 7
// 278.259 us; speedup vs baseline: 1.2909x; 1.2909x over previous
//
#include <hip/hip_runtime.h>

#define LIMG 4
#define CIN 256
#define HH 128
#define WW 256
#define HW 32768          // HH*WW
#define LHW 131072        // LIMG*HW
#define CD 128
#define KP 256
#define CAP 8192
#define NSP 2
#define CPER (CIN/NSP)    // 128
#define NINF -3.402823466e38f

// ---------------- fused: channel-reduced score planes + weight transpose + cnt ----------------
// blocks [0,1024): chanred ; blocks [1024, 1024+1152): wtrans (+cnt init)
__global__ __launch_bounds__(256) void k_chanred(const float* __restrict__ feats,
                                                 const float* __restrict__ wS,
                                                 float* __restrict__ g,
                                                 const float* __restrict__ wD,
                                                 float* __restrict__ wT,
                                                 int* __restrict__ cnt) {
  int bid = blockIdx.x;
  if (bid >= 1024) {
    int i = (bid - 1024) * 256 + threadIdx.x;
    if (i < LIMG) cnt[i] = 0;
    if (i < CD * CIN * 9) {
      int d = i & (CD - 1);
      int j = i >> 7;                    // c*9+tap
      wT[i] = wD[d * (CIN * 9) + j];
    }
    return;
  }
  int gp   = (bid & 511) * 256 + threadIdx.x;  // 0..131071
  int half = bid >> 9;                         // 0..NSP-1
  int l  = gp >> 15;
  int pi = gp & (HW - 1);
  const float* f = feats + (size_t)(l * CIN + half * CPER) * HW + pi;
  const float* w = wS + half * CPER * 9;
  float a0=0,a1=0,a2=0,a3=0,a4=0,a5=0,a6=0,a7=0,a8=0;
  #pragma unroll 4
  for (int c = 0; c < CPER; ++c) {
    float v = f[(size_t)c * HW];
    const float* wc = w + c * 9;
    a0 = fmaf(wc[0], v, a0); a1 = fmaf(wc[1], v, a1); a2 = fmaf(wc[2], v, a2);
    a3 = fmaf(wc[3], v, a3); a4 = fmaf(wc[4], v, a4); a5 = fmaf(wc[5], v, a5);
    a6 = fmaf(wc[6], v, a6); a7 = fmaf(wc[7], v, a7); a8 = fmaf(wc[8], v, a8);
  }
  float* go = g + (size_t)(half * 9) * LHW + gp;
  go[0*(size_t)LHW]=a0; go[1*(size_t)LHW]=a1; go[2*(size_t)LHW]=a2;
  go[3*(size_t)LHW]=a3; go[4*(size_t)LHW]=a4; go[5*(size_t)LHW]=a5;
  go[6*(size_t)LHW]=a6; go[7*(size_t)LHW]=a7; go[8*(size_t)LHW]=a8;
}

// ---------------- combine 9 shifted planes + bias + sigmoid ----------------
__global__ __launch_bounds__(256) void k_scores(const float* __restrict__ g,
                                                const float* __restrict__ bS,
                                                float* __restrict__ scores) {
  int gp = blockIdx.x * 256 + threadIdx.x;
  int l  = gp >> 15;
  int pi = gp & (HW - 1);
  int y = pi >> 8, x = pi & 255;
  float acc = bS[0];
  #pragma unroll
  for (int ky = 0; ky < 3; ++ky) {
    int yy = y + ky - 1;
    if (yy < 0 || yy >= HH) continue;
    #pragma unroll
    for (int kx = 0; kx < 3; ++kx) {
      int xx = x + kx - 1;
      if (xx < 0 || xx >= WW) continue;
      int tap = ky * 3 + kx;
      size_t q = (size_t)l * HW + yy * WW + xx;
      acc += g[(size_t)tap * LHW + q] + g[(size_t)(9 + tap) * LHW + q];
    }
  }
  scores[gp] = 1.0f / (1.0f + expf(-acc));
}

// ---------------- NMS stage 0: mask = (scores == pool9(scores)) ----------------
#define PROWS 8
__global__ __launch_bounds__(256) void k_nms0(const float* __restrict__ scores,
                                              float* __restrict__ mask) {
  __shared__ float raw[PROWS + 8][WW];
  __shared__ float rm[PROWS + 8][WW];
  int b = blockIdx.x;
  int l = b >> 4;
  int y0 = (b & 15) * PROWS;
  int x = threadIdx.x;
  const float* inl = scores + (size_t)l * HW;
  #pragma unroll
  for (int r = 0; r < PROWS + 8; ++r) {
    int yy = y0 - 4 + r;
    raw[r][x] = (yy >= 0 && yy < HH) ? inl[yy * WW + x] : NINF;
  }
  __syncthreads();
  #pragma unroll
  for (int r = 0; r < PROWS + 8; ++r) {
    float m = NINF;
    #pragma unroll
    for (int dx = -4; dx <= 4; ++dx) {
      int xx = x + dx;
      if (xx >= 0 && xx < WW) m = fmaxf(m, raw[r][xx]);
    }
    rm[r][x] = m;
  }
  __syncthreads();
  #pragma unroll
  for (int r = 0; r < PROWS; ++r) {
    float m = NINF;
    #pragma unroll
    for (int t = 0; t < 9; ++t) m = fmaxf(m, rm[r + t][x]);
    mask[l * HW + (y0 + r) * WW + x] = (m == raw[r + 4][x]) ? 1.0f : 0.0f;
  }
}

// ---------------- fused NMS iteration (supp -> supp_scores -> new_max -> mask') ----
// pad-0 is equivalent to reference pad(-inf): pooled values are >= 0 and every
// window contains its center pixel, so max / >0 outcomes are unchanged.
__global__ __launch_bounds__(256) void k_nmspair(const float* __restrict__ maskin,
                                                 const float* __restrict__ scores,
                                                 float* __restrict__ maskout,
                                                 int collect,
                                                 int* __restrict__ cnt,
                                                 int* __restrict__ cidx,
                                                 float* __restrict__ csc) {
  __shared__ float m24[PROWS + 16][WW];
  __shared__ float rm[PROWS + 16][WW];
  __shared__ float ss[PROWS + 8][WW];
  __shared__ float rs[PROWS + 8][WW];
  __shared__ float smc[PROWS][WW];
  int b = blockIdx.x;
  int l = b >> 4;
  int y0 = (b & 15) * PROWS;
  int x = threadIdx.x;
  const float* ml = maskin + (size_t)l * HW;
  const float* sl = scores + (size_t)l * HW;
  #pragma unroll
  for (int r = 0; r < PROWS + 16; ++r) {
    int yy = y0 - 8 + r;
    m24[r][x] = (yy >= 0 && yy < HH) ? ml[yy * WW + x] : 0.0f;
  }
  __syncthreads();
  #pragma unroll
  for (int r = 0; r < PROWS + 16; ++r) {
    float m = 0.0f;
    #pragma unroll
    for (int dx = -4; dx <= 4; ++dx) {
      int xx = x + dx;
      if (xx >= 0 && xx < WW) m = fmaxf(m, m24[r][xx]);
    }
    rm[r][x] = m;
  }
  __syncthreads();
  #pragma unroll
  for (int r2 = 0; r2 < PROWS + 8; ++r2) {
    float m = 0.0f;
    #pragma unroll
    for (int t = 0; t < 9; ++t) m = fmaxf(m, rm[r2 + t][x]);
    bool sm = m > 0.0f;
    int yy = y0 - 4 + r2;
    float sv = (yy >= 0 && yy < HH) ? sl[yy * WW + x] : 0.0f;
    ss[r2][x] = sm ? 0.0f : sv;
    if (r2 >= 4 && r2 < 4 + PROWS) smc[r2 - 4][x] = sm ? 1.0f : 0.0f;
  }
  __syncthreads();
  #pragma unroll
  for (int r2 = 0; r2 < PROWS + 8; ++r2) {
    float m = NINF;
    #pragma unroll
    for (int dx = -4; dx <= 4; ++dx) {
      int xx = x + dx;
      if (xx >= 0 && xx < WW) m = fmaxf(m, ss[r2][xx]);
    }
    rs[r2][x] = m;
  }
  __syncthreads();
  #pragma unroll
  for (int r = 0; r < PROWS; ++r) {
    float m = NINF;
    #pragma unroll
    for (int t = 0; t < 9; ++t) m = fmaxf(m, rs[r + t][x]);
    bool nm = (ss[r + 4][x] == m) && (smc[r][x] == 0.0f);
    float prev = m24[r + 8][x];
    float outv = (prev != 0.0f || nm) ? 1.0f : 0.0f;
    int p = (y0 + r) * WW + x;
    maskout[l * HW + p] = outv;
    if (collect && outv != 0.0f) {
      int pos = atomicAdd(&cnt[l], 1);
      if (pos < CAP) {
        cidx[l * CAP + pos] = p;
        csc[l * CAP + pos]  = sl[p];
      }
    }
  }
}

// ---------------- rank-based stable top-k + zero-score fill ----------------
__global__ __launch_bounds__(256) void k_rankfill(const int* __restrict__ cnt,
                                                  const int* __restrict__ cidx,
                                                  const float* __restrict__ csc,
                                                  const float* __restrict__ mask,
                                                  int* __restrict__ sel) {
  __shared__ unsigned long long keys[CAP];   // 64 KiB
  __shared__ int csum[256];
  int b = blockIdx.x;            // 32 blocks: 8 per image
  int l = b >> 3;
  int tid = threadIdx.x;
  int M = cnt[l]; if (M > CAP) M = CAP;
  const int* ci = cidx + l * CAP;
  const float* cs = csc + l * CAP;
  for (int j = tid; j < M; j += 256) {
    unsigned int ks = __float_as_uint(cs[j]);   // scores > 0 -> bits monotone
    keys[j] = ((unsigned long long)(0xFFFFFFFFu - ks) << 32) | (unsigned int)ci[j];
  }
  __syncthreads();
  for (int i = (b & 7) * 256 + tid; i < M; i += 2048) {
    unsigned long long ki = keys[i];
    int rank = 0;
    for (int j = 0; j < M; ++j)
      rank += (keys[j] < ki) ? 1 : 0;
    if (rank < KP) sel[l * KP + rank] = (int)(unsigned int)(ki & 0xFFFFFFFFu);
  }
  if ((b & 7) != 0) return;
  int Mc = (M < KP) ? M : KP;
  int need = KP - Mc;
  if (need > 0) {
    const float* mk = mask + (size_t)l * HW;
    const int per = HW / 256;               // 128
    int base = tid * per;
    int c = 0;
    for (int q = 0; q < per; ++q) c += (mk[base + q] == 0.0f) ? 1 : 0;
    int inc = c;
    csum[tid] = c;
    __syncthreads();
    for (int s = 1; s < 256; s <<= 1) {
      int v = (tid >= s) ? csum[tid - s] : 0;
      __syncthreads();
      csum[tid] += v;
      __syncthreads();
    }
    int excl = csum[tid] - inc;
    if (excl < need) {
      int r = excl;
      for (int q = 0; q < per && r < need; ++q) {
        if (mk[base + q] == 0.0f) { sel[l * KP + Mc + r] = base + q; ++r; }
      }
    }
  }
}

// ---------------- desc conv phase 1: 32 kp / block, 8-way channel split ----------------
// grid: q(8) x kb(8) x l(4) = 256 blocks, 256 threads. pacc[q][l][k][d]
__global__ __launch_bounds__(256) void k_desc1(const float* __restrict__ feats,
                                               const float* __restrict__ wT,
                                               const int* __restrict__ sel,
                                               float* __restrict__ pacc) {
  __shared__ float patch[32][288];     // 36.9 KiB
  __shared__ int kpix[32];
  int b = blockIdx.x;
  int q  = b & 7;
  int kb = (b >> 3) & 7;
  int l  = b >> 6;
  int k0 = kb * 32;
  int tid = threadIdx.x;
  if (tid < 32) kpix[tid] = sel[l * KP + k0 + tid];
  __syncthreads();
  int c0 = q * 32;
  for (int e = tid; e < 32 * 288; e += 256) {
    int kp = e / 288;
    int j  = e - kp * 288;
    int c  = j / 9;
    int tap = j - c * 9;
    int ky = tap / 3, kx = tap - ky * 3;
    int pix = kpix[kp];
    int y = pix >> 8, x = pix & 255;
    int yy = y + ky - 1, xx = x + kx - 1;
    float v = 0.0f;
    if (yy >= 0 && yy < HH && xx >= 0 && xx < WW)
      v = feats[((size_t)(l * CIN + c0 + c) * HH + yy) * WW + xx];
    patch[kp][j] = v;
  }
  __syncthreads();
  int d = tid & 127;
  int gg = tid >> 7;                    // kp group of 16
  const float* w = wT + (size_t)(q * 288) * CD + d;
  float a[16];
  #pragma unroll
  for (int i = 0; i < 16; ++i) a[i] = 0.0f;
  #pragma unroll 2
  for (int j = 0; j < 288; j += 4) {
    float w0 = w[(size_t)(j + 0) * CD];
    float w1 = w[(size_t)(j + 1) * CD];
    float w2 = w[(size_t)(j + 2) * CD];
    float w3 = w[(size_t)(j + 3) * CD];
    #pragma unroll
    for (int i = 0; i < 16; ++i) {
      float4 qv = *(const float4*)&patch[16 * gg + i][j];
      a[i] = fmaf(w0, qv.x, a[i]);
      a[i] = fmaf(w1, qv.y, a[i]);
      a[i] = fmaf(w2, qv.z, a[i]);
      a[i] = fmaf(w3, qv.w, a[i]);
    }
  }
  size_t base = (((size_t)q * LIMG + l) * KP + k0 + 16 * gg) * CD + d;
  #pragma unroll
  for (int i = 0; i < 16; ++i)
    pacc[base + (size_t)i * CD] = a[i];
}

// ---------------- fused: combine 8 partials + bias + relu + L2 norm + attention ----------------
__global__ __launch_bounds__(128) void k_desc2attn(const float* __restrict__ pacc,
                                                   const float* __restrict__ bD,
                                                   float* __restrict__ d2) {
  __shared__ float ps[2][LIMG];
  __shared__ float qs[LIMG][CD];
  __shared__ float dm[16];
  int k = blockIdx.x;
  int d = threadIdx.x;
  float bv = bD[d];
  float r[LIMG];
  #pragma unroll
  for (int l = 0; l < LIMG; ++l) {
    float s = bv;
    #pragma unroll
    for (int qq = 0; qq < 8; ++qq)
      s += pacc[(((size_t)qq * LIMG + l) * KP + k) * CD + d];
    r[l] = fmaxf(s, 0.0f);
  }
  int lane = d & 63, wid = d >> 6;
  #pragma unroll
  for (int l = 0; l < LIMG; ++l) {
    float v = r[l] * r[l];
    #pragma unroll
    for (int sh = 32; sh > 0; sh >>= 1) v += __shfl_down(v, sh);
    if (lane == 0) ps[wid][l] = v;
  }
  __syncthreads();
  float q[LIMG];
  #pragma unroll
  for (int l = 0; l < LIMG; ++l) {
    float n = fmaxf(sqrtf(ps[0][l] + ps[1][l]), 1e-12f);
    q[l] = r[l] / n;
    qs[l][d] = q[l];
  }
  __syncthreads();
  if (d < 16) {
    int n = d >> 2, m = d & 3;
    float s = 0.f;
    for (int t = 0; t < CD; ++t) s = fmaf(qs[n][t], qs[m][t], s);
    dm[d] = s * 0.08838834764831843f;     // 1/sqrt(128)
  }
  __syncthreads();
  #pragma unroll
  for (int n = 0; n < LIMG; ++n) {
    float a0 = dm[n*4+0], a1 = dm[n*4+1], a2 = dm[n*4+2], a3 = dm[n*4+3];
    float mx = fmaxf(fmaxf(a0, a1), fmaxf(a2, a3));
    float e0 = expf(a0 - mx), e1 = expf(a1 - mx), e2 = expf(a2 - mx), e3 = expf(a3 - mx);
    float inv = 1.0f / (e0 + e1 + e2 + e3);
    float msg = (e0 * q[0] + e1 * q[1] + e2 * q[2] + e3 * q[3]) * inv;
    d2[(size_t)(n * CD + d) * KP + k] = 2.0f * q[n] + msg;
  }
}

// ---------------- conv1d k=3 pad=1 + relu ----------------
__global__ __launch_bounds__(256) void k_proj(const float* __restrict__ d2, const float* __restrict__ pw,
                                              const float* __restrict__ pb, float* __restrict__ d3) {
  int b = blockIdx.x;
  int l = b >> 7, o = b & 127;
  int k = threadIdx.x;
  float acc = pb[o];
  for (int c = 0; c < CD; ++c) {
    const float* row = d2 + (size_t)(l * CD + c) * KP;
    float xm = (k > 0)      ? row[k - 1] : 0.f;
    float x0 = row[k];
    float xp = (k < KP - 1) ? row[k + 1] : 0.f;
    const float* w = pw + (size_t)(o * CD + c) * 3;
    acc = fmaf(w[0], xm, acc);
    acc = fmaf(w[1], x0, acc);
    acc = fmaf(w[2], xp, acc);
  }
  d3[(size_t)(l * CD + o) * KP + k] = fmaxf(acc, 0.f);
}

// ---------------- fused: conv1d k=1 + stable descending argsort + gather ----------------
__global__ __launch_bounds__(256) void k_projsort(const float* __restrict__ d3,
                                                  const float* __restrict__ psw,
                                                  const float* __restrict__ psb,
                                                  float* __restrict__ d4) {
  int b = blockIdx.x;
  int l = b >> 7, o = b & 127;
  int k = threadIdx.x;
  __shared__ float srow[KP];
  float acc = psb[o];
  for (int c = 0; c < CD; ++c)
    acc = fmaf(psw[o * CD + c], d3[(size_t)(l * CD + c) * KP + k], acc);
  srow[k] = acc;
  __syncthreads();
  int rank = 0;
  for (int m = 0; m < KP; ++m) {
    float sm = srow[m];
    rank += (sm > acc || (sm == acc && m < k)) ? 1 : 0;
  }
  int base = (l * CD + o) * KP;
  d4[base + rank] = d3[base + k];
}

// ---------------- fused: final conv1d (128->3) + min|diff| -> theta ----------------
__global__ __launch_bounds__(1024) void k_finaltheta(const float* __restrict__ d4,
                                                     const float* __restrict__ fw,
                                                     const float* __restrict__ fb,
                                                     float* __restrict__ theta) {
  __shared__ float accs[LIMG][KP][3];
  __shared__ float res[LIMG][3];
  int tid = threadIdx.x;
  int l = tid >> 8, k = tid & 255;
  float a0 = fb[0], a1 = fb[1], a2 = fb[2];
  const float* dl = d4 + (size_t)l * CD * KP + k;
  for (int c = 0; c < CD; ++c) {
    float v = dl[(size_t)c * KP];
    a0 = fmaf(fw[0 * CD + c], v, a0);
    a1 = fmaf(fw[1 * CD + c], v, a1);
    a2 = fmaf(fw[2 * CD + c], v, a2);
  }
  accs[l][k][0] = a0; accs[l][k][1] = a1; accs[l][k][2] = a2;
  __syncthreads();
  int wid = tid >> 6, lane = tid & 63;
  if (wid < 12) {
    int rl = wid / 3, ro = wid - rl * 3;
    float m = 3.402823466e38f;
    #pragma unroll
    for (int t = 0; t < 4; ++t) {
      int kk = lane + 64 * t;
      m = fminf(m, fabsf(accs[rl][kk][ro] - accs[0][kk][ro]));
    }
    #pragma unroll
    for (int s = 32; s > 0; s >>= 1) m = fminf(m, __shfl_down(m, s));
    if (lane == 0) res[rl][ro] = m;
  }
  __syncthreads();
  if (tid == 0) {
    for (int l2 = 0; l2 < LIMG; ++l2) {
      float tx = res[l2][0], ty = res[l2][1], th = res[l2][2];
      float cth = cosf(th), sth = sinf(th);
      theta[l2*6+0] = cth;  theta[l2*6+1] = -sth; theta[l2*6+2] = tx;
      theta[l2*6+3] = sth;  theta[l2*6+4] = cth;  theta[l2*6+5] = ty;
    }
  }
}

// ---------------- bilinear grid sample: 8 channels per thread ----------------
__global__ __launch_bounds__(256) void k_sample(const float* __restrict__ feats,
                                                const float* __restrict__ theta,
                                                float* __restrict__ out) {
  int b = blockIdx.x;
  int pb = b & 127;
  int cg = (b >> 7) & 31;
  int l  = b >> 12;
  int pi = pb * 256 + threadIdx.x;
  int x = pi & 255, y = pi >> 8;
  const float* t = theta + l * 6;
  float X = (x + 0.5f) * (2.0f / WW) - 1.0f;
  float Y = (y + 0.5f) * (2.0f / HH) - 1.0f;
  float gx = t[0] * X + t[1] * Y + t[2];
  float gy = t[3] * X + t[4] * Y + t[5];
  float ix = ((gx + 1.0f) * WW - 1.0f) * 0.5f;
  float iy = ((gy + 1.0f) * HH - 1.0f) * 0.5f;
  float x0 = floorf(ix), y0 = floorf(iy);
  float x1 = x0 + 1.0f,  y1 = y0 + 1.0f;
  float wa = (x1 - ix) * (y1 - iy);
  float wb = (ix - x0) * (y1 - iy);
  float wc = (x1 - ix) * (iy - y0);
  float wd = (ix - x0) * (iy - y0);
  bool vx0 = (x0 >= 0.f) && (x0 <= (float)(WW-1));
  bool vx1 = (x1 >= 0.f) && (x1 <= (float)(WW-1));
  bool vy0 = (y0 >= 0.f) && (y0 <= (float)(HH-1));
  bool vy1 = (y1 >= 0.f) && (y1 <= (float)(HH-1));
  wa = (vx0 && vy0) ? wa : 0.f;
  wb = (vx1 && vy0) ? wb : 0.f;
  wc = (vx0 && vy1) ? wc : 0.f;
  wd = (vx1 && vy1) ? wd : 0.f;
  int xc0 = (int)fminf(fmaxf(x0, 0.f), (float)(WW-1));
  int xc1 = (int)fminf(fmaxf(x1, 0.f), (float)(WW-1));
  int yc0 = (int)fminf(fmaxf(y0, 0.f), (float)(HH-1));
  int yc1 = (int)fminf(fmaxf(y1, 0.f), (float)(HH-1));
  int o00 = yc0 * WW + xc0;
  int o10 = yc0 * WW + xc1;
  int o01 = yc1 * WW + xc0;
  int o11 = yc1 * WW + xc1;
  const float* img = feats + (size_t)(l * CIN + cg * 8) * HW;
  float* op = out + (size_t)(l * CIN + cg * 8) * HW + pi;
  #pragma unroll
  for (int i = 0; i < 8; ++i) {
    const float* im = img + (size_t)i * HW;
    float acc = im[o00] * wa + im[o10] * wb + im[o01] * wc + im[o11] * wd;
    op[(size_t)i * HW] = acc;
  }
}

extern "C" void kernel_launch(void* const* d_in, const int* in_sizes, int n_in,
                              void* d_out, int out_size, void* d_ws, size_t ws_size,
                              hipStream_t stream) {
  const float* feats = (const float*)d_in[0];
  const float* wS    = (const float*)d_in[1];
  const float* bS    = (const float*)d_in[2];
  const float* wD    = (const float*)d_in[3];
  const float* bD    = (const float*)d_in[4];
  const float* pw    = (const float*)d_in[5];
  const float* pb    = (const float*)d_in[6];
  const float* psw   = (const float*)d_in[7];
  const float* psb   = (const float*)d_in[8];
  const float* fw    = (const float*)d_in[9];
  const float* fb    = (const float*)d_in[10];
  float* out = (float*)d_out;

  char* base = (char*)d_ws;
  size_t off = 0;
  auto alloc = [&](size_t bytes) -> void* {
    void* p = base + off;
    off = (off + bytes + 255) & ~(size_t)255;
    return p;
  };
  float* g      = (float*)alloc((size_t)NSP * 9 * LHW * sizeof(float));
  float* scores = (float*)alloc((size_t)LHW * 4);
  float* maskA  = (float*)alloc((size_t)LHW * 4);
  float* maskB  = (float*)alloc((size_t)LHW * 4);
  float* d2     = (float*)alloc((size_t)LHW * 4);
  float* d3     = (float*)alloc((size_t)LHW * 4);
  float* d4     = (float*)alloc((size_t)LHW * 4);
  float* wT     = (float*)alloc((size_t)CIN * 9 * CD * 4);
  float* pacc   = (float*)alloc((size_t)8 * LIMG * KP * CD * 4);
  float* theta  = (float*)alloc(24 * 4);
  float* csc    = (float*)alloc((size_t)LIMG * CAP * 4);
  int*   cidx   = (int*)  alloc((size_t)LIMG * CAP * 4);
  int*   cnt    = (int*)  alloc(64);
  int*   sel    = (int*)  alloc((size_t)LIMG * KP * 4);

  const int WT_BLOCKS = (CD * CIN * 9 + 255) / 256;   // 1152
  k_chanred<<<1024 + WT_BLOCKS, 256, 0, stream>>>(feats, wS, g, wD, wT, cnt);
  k_scores<<<512, 256, 0, stream>>>(g, bS, scores);
  k_nms0<<<64, 256, 0, stream>>>(scores, maskA);
  k_nmspair<<<64, 256, 0, stream>>>(maskA, scores, maskB, 0, cnt, cidx, csc);
  k_nmspair<<<64, 256, 0, stream>>>(maskB, scores, maskA, 1, cnt, cidx, csc);
  k_rankfill<<<32, 256, 0, stream>>>(cnt, cidx, csc, maskA, sel);
  k_desc1<<<256, 256, 0, stream>>>(feats, wT, sel, pacc);
  k_desc2attn<<<256, 128, 0, stream>>>(pacc, bD, d2);
  k_proj<<<512, 256, 0, stream>>>(d2, pw, pb, d3);
  k_projsort<<<512, 256, 0, stream>>>(d3, psw, psb, d4);
  k_finaltheta<<<1, 1024, 0, stream>>>(d4, fw, fb, theta);
  k_sample<<<16384, 256, 0, stream>>>(feats, theta, out);
}

// Round 8
// 235.308 us; speedup vs baseline: 1.5266x; 1.1825x over previous
//
#include <hip/hip_runtime.h>

#define LIMG 4
#define CIN 256
#define HH 128
#define WW 256
#define HW 32768          // HH*WW
#define LHW 131072        // LIMG*HW
#define CD 128
#define KP 256
#define CAP 8192
#define NSP 2
#define CPER (CIN/NSP)    // 128
#define NINF -3.402823466e38f

// ---------------- fused: channel-reduced score planes + weight transpose + cnt ----------------
// blocks [0,1024): chanred ; blocks [1024, 1024+1152): wtrans (+cnt init)
__global__ __launch_bounds__(256) void k_chanred(const float* __restrict__ feats,
                                                 const float* __restrict__ wS,
                                                 float* __restrict__ g,
                                                 const float* __restrict__ wD,
                                                 float* __restrict__ wT,
                                                 int* __restrict__ cnt) {
  int bid = blockIdx.x;
  if (bid >= 1024) {
    int i = (bid - 1024) * 256 + threadIdx.x;
    if (i < LIMG) cnt[i] = 0;
    if (i < CD * CIN * 9) {
      int d = i & (CD - 1);
      int j = i >> 7;                    // c*9+tap
      wT[i] = wD[d * (CIN * 9) + j];
    }
    return;
  }
  int gp   = (bid & 511) * 256 + threadIdx.x;  // 0..131071
  int half = bid >> 9;                         // 0..NSP-1
  int l  = gp >> 15;
  int pi = gp & (HW - 1);
  const float* f = feats + (size_t)(l * CIN + half * CPER) * HW + pi;
  const float* w = wS + half * CPER * 9;
  float a0=0,a1=0,a2=0,a3=0,a4=0,a5=0,a6=0,a7=0,a8=0;
  #pragma unroll 4
  for (int c = 0; c < CPER; ++c) {
    float v = f[(size_t)c * HW];
    const float* wc = w + c * 9;
    a0 = fmaf(wc[0], v, a0); a1 = fmaf(wc[1], v, a1); a2 = fmaf(wc[2], v, a2);
    a3 = fmaf(wc[3], v, a3); a4 = fmaf(wc[4], v, a4); a5 = fmaf(wc[5], v, a5);
    a6 = fmaf(wc[6], v, a6); a7 = fmaf(wc[7], v, a7); a8 = fmaf(wc[8], v, a8);
  }
  float* go = g + (size_t)(half * 9) * LHW + gp;
  go[0*(size_t)LHW]=a0; go[1*(size_t)LHW]=a1; go[2*(size_t)LHW]=a2;
  go[3*(size_t)LHW]=a3; go[4*(size_t)LHW]=a4; go[5*(size_t)LHW]=a5;
  go[6*(size_t)LHW]=a6; go[7*(size_t)LHW]=a7; go[8*(size_t)LHW]=a8;
}

// ---------------- combine 9 shifted planes + bias + sigmoid ----------------
__global__ __launch_bounds__(256) void k_scores(const float* __restrict__ g,
                                                const float* __restrict__ bS,
                                                float* __restrict__ scores) {
  int gp = blockIdx.x * 256 + threadIdx.x;
  int l  = gp >> 15;
  int pi = gp & (HW - 1);
  int y = pi >> 8, x = pi & 255;
  float acc = bS[0];
  #pragma unroll
  for (int ky = 0; ky < 3; ++ky) {
    int yy = y + ky - 1;
    if (yy < 0 || yy >= HH) continue;
    #pragma unroll
    for (int kx = 0; kx < 3; ++kx) {
      int xx = x + kx - 1;
      if (xx < 0 || xx >= WW) continue;
      int tap = ky * 3 + kx;
      size_t q = (size_t)l * HW + yy * WW + xx;
      acc += g[(size_t)tap * LHW + q] + g[(size_t)(9 + tap) * LHW + q];
    }
  }
  scores[gp] = 1.0f / (1.0f + expf(-acc));
}

// ---------------- fused NMS: mask0 + iteration 1, x-tiled ----------------
// grid: l(4) x ytile(16) x xtile(2) = 128 blocks, 256 threads.
// Reads precomputed scores (L2) with halo 12; writes mask-after-iter1 rows
// [y0,y0+8) cols [x0,x0+128). Pools of mask/supp use pad-0 == reference
// pad(-inf) (values >= 0, window always contains in-image center).
__global__ __launch_bounds__(256) void k_nms01(const float* __restrict__ scores,
                                               float* __restrict__ maskout) {
  __shared__ float sS[32][152];   // scores rows y0-12.., cols x0-12..
  __shared__ float buf[32][152];  // reusable row-pool scratch
  __shared__ float sM[24][144];   // mask0 rows y0-8.., cols x0-8..
  __shared__ float ss[16][136];   // supp_scores rows y0-4.., cols x0-4..
  __shared__ float smc[8][128];   // suppm at center rows/cols
  int b = blockIdx.x;
  int l  = b >> 5;
  int yt = (b >> 1) & 15;
  int xt = b & 1;
  int y0 = yt * 8;
  int x0 = xt * 128;
  int tid = threadIdx.x;
  const float* sl = scores + (size_t)l * HW;
  if (tid < 152) {
    int gx = x0 - 12 + tid;
    bool vx = (gx >= 0 && gx < WW);
    for (int r = 0; r < 32; ++r) {
      int gy = y0 - 12 + r;
      sS[r][tid] = (vx && gy >= 0 && gy < HH) ? sl[gy * WW + gx] : NINF;
    }
  }
  __syncthreads();
  if (tid < 144) {                       // rowmax of scores
    for (int r = 0; r < 32; ++r) {
      float m = sS[r][tid];
      #pragma unroll
      for (int dx = 1; dx <= 8; ++dx) m = fmaxf(m, sS[r][tid + dx]);
      buf[r][tid] = m;
    }
  }
  __syncthreads();
  if (tid < 144) {                       // mask0
    int gx = x0 - 8 + tid;
    bool vx = (gx >= 0 && gx < WW);
    for (int r3 = 0; r3 < 24; ++r3) {
      int gy = y0 - 8 + r3;
      float m = buf[r3][tid];
      #pragma unroll
      for (int t = 1; t < 9; ++t) m = fmaxf(m, buf[r3 + t][tid]);
      sM[r3][tid] = (vx && gy >= 0 && gy < HH && sS[r3 + 4][tid + 4] == m) ? 1.0f : 0.0f;
    }
  }
  __syncthreads();
  if (tid < 136) {                       // rowpool of mask0
    for (int r3 = 0; r3 < 24; ++r3) {
      float m = sM[r3][tid];
      #pragma unroll
      for (int dx = 1; dx <= 8; ++dx) m = fmaxf(m, sM[r3][tid + dx]);
      buf[r3][tid] = m;
    }
  }
  __syncthreads();
  if (tid < 136) {                       // supp mask + supp scores
    int gx = x0 - 4 + tid;
    bool vx = (gx >= 0 && gx < WW);
    for (int r2 = 0; r2 < 16; ++r2) {
      int gy = y0 - 4 + r2;
      float m = buf[r2][tid];
      #pragma unroll
      for (int t = 1; t < 9; ++t) m = fmaxf(m, buf[r2 + t][tid]);
      bool sm = m > 0.0f;
      bool vin = vx && gy >= 0 && gy < HH;
      ss[r2][tid] = (sm || !vin) ? 0.0f : sS[r2 + 8][tid + 8];
      if (r2 >= 4 && r2 < 12 && tid >= 4 && tid < 132)
        smc[r2 - 4][tid - 4] = sm ? 1.0f : 0.0f;
    }
  }
  __syncthreads();
  if (tid < 128) {                       // rowmax of supp scores
    for (int r2 = 0; r2 < 16; ++r2) {
      float m = ss[r2][tid];
      #pragma unroll
      for (int dx = 1; dx <= 8; ++dx) m = fmaxf(m, ss[r2][tid + dx]);
      buf[r2][tid] = m;
    }
  }
  __syncthreads();
  if (tid < 128) {                       // colmax + combine
    int gx = x0 + tid;
    for (int r = 0; r < 8; ++r) {
      float m = buf[r][tid];
      #pragma unroll
      for (int t = 1; t < 9; ++t) m = fmaxf(m, buf[r + t][tid]);
      bool nm = (ss[r + 4][tid + 4] == m) && (smc[r][tid] == 0.0f);
      float prev = sM[r + 8][tid + 8];
      maskout[l * HW + (y0 + r) * WW + gx] = (prev != 0.0f || nm) ? 1.0f : 0.0f;
    }
  }
}

// ---------------- NMS iteration 2 + candidate collect, x-tiled ----------------
__global__ __launch_bounds__(256) void k_nms2(const float* __restrict__ maskin,
                                              const float* __restrict__ scores,
                                              float* __restrict__ maskout,
                                              int* __restrict__ cnt,
                                              int* __restrict__ cidx,
                                              float* __restrict__ csc) {
  __shared__ float m24[24][144];
  __shared__ float buf[24][144];
  __shared__ float ss[16][136];
  __shared__ float smc[8][128];
  int b = blockIdx.x;
  int l  = b >> 5;
  int yt = (b >> 1) & 15;
  int xt = b & 1;
  int y0 = yt * 8;
  int x0 = xt * 128;
  int tid = threadIdx.x;
  const float* ml = maskin + (size_t)l * HW;
  const float* sl = scores + (size_t)l * HW;
  if (tid < 144) {
    int gx = x0 - 8 + tid;
    bool vx = (gx >= 0 && gx < WW);
    for (int r = 0; r < 24; ++r) {
      int gy = y0 - 8 + r;
      m24[r][tid] = (vx && gy >= 0 && gy < HH) ? ml[gy * WW + gx] : 0.0f;
    }
  }
  __syncthreads();
  if (tid < 136) {                       // rowpool of mask
    for (int r = 0; r < 24; ++r) {
      float m = m24[r][tid];
      #pragma unroll
      for (int dx = 1; dx <= 8; ++dx) m = fmaxf(m, m24[r][tid + dx]);
      buf[r][tid] = m;
    }
  }
  __syncthreads();
  if (tid < 136) {                       // supp mask + supp scores
    int gx = x0 - 4 + tid;
    bool vx = (gx >= 0 && gx < WW);
    for (int r2 = 0; r2 < 16; ++r2) {
      int gy = y0 - 4 + r2;
      float m = buf[r2][tid];
      #pragma unroll
      for (int t = 1; t < 9; ++t) m = fmaxf(m, buf[r2 + t][tid]);
      bool sm = m > 0.0f;
      bool vin = vx && gy >= 0 && gy < HH;
      ss[r2][tid] = (sm || !vin) ? 0.0f : sl[gy * WW + gx];
      if (r2 >= 4 && r2 < 12 && tid >= 4 && tid < 132)
        smc[r2 - 4][tid - 4] = sm ? 1.0f : 0.0f;
    }
  }
  __syncthreads();
  if (tid < 128) {                       // rowmax of supp scores
    for (int r2 = 0; r2 < 16; ++r2) {
      float m = ss[r2][tid];
      #pragma unroll
      for (int dx = 1; dx <= 8; ++dx) m = fmaxf(m, ss[r2][tid + dx]);
      buf[r2][tid] = m;
    }
  }
  __syncthreads();
  if (tid < 128) {                       // colmax + combine + collect
    int gx = x0 + tid;
    for (int r = 0; r < 8; ++r) {
      float m = buf[r][tid];
      #pragma unroll
      for (int t = 1; t < 9; ++t) m = fmaxf(m, buf[r + t][tid]);
      bool nm = (ss[r + 4][tid + 4] == m) && (smc[r][tid] == 0.0f);
      float prev = m24[r + 8][tid + 8];
      float outv = (prev != 0.0f || nm) ? 1.0f : 0.0f;
      int p = (y0 + r) * WW + gx;
      maskout[l * HW + p] = outv;
      if (outv != 0.0f) {
        int pos = atomicAdd(&cnt[l], 1);
        if (pos < CAP) {
          cidx[l * CAP + pos] = p;
          csc[l * CAP + pos]  = sl[p];
        }
      }
    }
  }
}

// ---------------- rank-based stable top-k + zero-score fill ----------------
__global__ __launch_bounds__(256) void k_rankfill(const int* __restrict__ cnt,
                                                  const int* __restrict__ cidx,
                                                  const float* __restrict__ csc,
                                                  const float* __restrict__ mask,
                                                  int* __restrict__ sel) {
  __shared__ unsigned long long keys[CAP];   // 64 KiB
  __shared__ int csum[256];
  int b = blockIdx.x;            // 32 blocks: 8 per image
  int l = b >> 3;
  int tid = threadIdx.x;
  int M = cnt[l]; if (M > CAP) M = CAP;
  const int* ci = cidx + l * CAP;
  const float* cs = csc + l * CAP;
  for (int j = tid; j < M; j += 256) {
    unsigned int ks = __float_as_uint(cs[j]);   // scores > 0 -> bits monotone
    keys[j] = ((unsigned long long)(0xFFFFFFFFu - ks) << 32) | (unsigned int)ci[j];
  }
  __syncthreads();
  for (int i = (b & 7) * 256 + tid; i < M; i += 2048) {
    unsigned long long ki = keys[i];
    int rank = 0;
    for (int j = 0; j < M; ++j)
      rank += (keys[j] < ki) ? 1 : 0;
    if (rank < KP) sel[l * KP + rank] = (int)(unsigned int)(ki & 0xFFFFFFFFu);
  }
  if ((b & 7) != 0) return;
  int Mc = (M < KP) ? M : KP;
  int need = KP - Mc;
  if (need > 0) {
    const float* mk = mask + (size_t)l * HW;
    const int per = HW / 256;               // 128
    int base = tid * per;
    int c = 0;
    for (int q = 0; q < per; ++q) c += (mk[base + q] == 0.0f) ? 1 : 0;
    int inc = c;
    csum[tid] = c;
    __syncthreads();
    for (int s = 1; s < 256; s <<= 1) {
      int v = (tid >= s) ? csum[tid - s] : 0;
      __syncthreads();
      csum[tid] += v;
      __syncthreads();
    }
    int excl = csum[tid] - inc;
    if (excl < need) {
      int r = excl;
      for (int q = 0; q < per && r < need; ++q) {
        if (mk[base + q] == 0.0f) { sel[l * KP + Mc + r] = base + q; ++r; }
      }
    }
  }
}

// ---------------- desc conv phase 1: split-K partials, 16 kp / block ----------------
// grid: q(4) x kb(16) x l(4) = 256 blocks, 256 threads. pacc[q][l][k][d]
__global__ __launch_bounds__(256) void k_desc1(const float* __restrict__ feats,
                                               const float* __restrict__ wT,
                                               const int* __restrict__ sel,
                                               float* __restrict__ pacc) {
  __shared__ float patch[16][576];     // 36.9 KiB
  __shared__ int kpix[16];
  int b = blockIdx.x;
  int q  = b & 3;
  int kb = (b >> 2) & 15;
  int l  = b >> 6;
  int k0 = kb * 16;
  int tid = threadIdx.x;
  if (tid < 16) kpix[tid] = sel[l * KP + k0 + tid];
  __syncthreads();
  int c0 = q * 64;
  for (int e = tid; e < 16 * 576; e += 256) {
    int kp = e / 576;
    int j  = e - kp * 576;
    int c  = j / 9;
    int tap = j - c * 9;
    int ky = tap / 3, kx = tap - ky * 3;
    int pix = kpix[kp];
    int y = pix >> 8, x = pix & 255;
    int yy = y + ky - 1, xx = x + kx - 1;
    float v = 0.0f;
    if (yy >= 0 && yy < HH && xx >= 0 && xx < WW)
      v = feats[((size_t)(l * CIN + c0 + c) * HH + yy) * WW + xx];
    patch[kp][j] = v;
  }
  __syncthreads();
  int d = tid & 127;
  int gg = tid >> 7;                    // kp group of 8
  const float* w = wT + (size_t)(q * 576) * CD + d;
  float a[8] = {0.f,0.f,0.f,0.f,0.f,0.f,0.f,0.f};
  #pragma unroll 2
  for (int j = 0; j < 576; j += 4) {
    float w0 = w[(size_t)(j + 0) * CD];
    float w1 = w[(size_t)(j + 1) * CD];
    float w2 = w[(size_t)(j + 2) * CD];
    float w3 = w[(size_t)(j + 3) * CD];
    #pragma unroll
    for (int i = 0; i < 8; ++i) {
      float4 qv = *(const float4*)&patch[8 * gg + i][j];
      a[i] = fmaf(w0, qv.x, a[i]);
      a[i] = fmaf(w1, qv.y, a[i]);
      a[i] = fmaf(w2, qv.z, a[i]);
      a[i] = fmaf(w3, qv.w, a[i]);
    }
  }
  size_t base = (((size_t)q * LIMG + l) * KP + k0 + 8 * gg) * CD + d;
  #pragma unroll
  for (int i = 0; i < 8; ++i)
    pacc[base + (size_t)i * CD] = a[i];
}

// ---------------- fused: combine 4 partials + bias + relu + L2 norm + attention ----------------
__global__ __launch_bounds__(128) void k_desc2attn(const float* __restrict__ pacc,
                                                   const float* __restrict__ bD,
                                                   float* __restrict__ d2) {
  __shared__ float ps[2][LIMG];
  __shared__ float qs[LIMG][CD];
  __shared__ float dm[16];
  int k = blockIdx.x;
  int d = threadIdx.x;
  float bv = bD[d];
  float r[LIMG];
  #pragma unroll
  for (int l = 0; l < LIMG; ++l) {
    float s = bv;
    #pragma unroll
    for (int qq = 0; qq < 4; ++qq)
      s += pacc[(((size_t)qq * LIMG + l) * KP + k) * CD + d];
    r[l] = fmaxf(s, 0.0f);
  }
  int lane = d & 63, wid = d >> 6;
  #pragma unroll
  for (int l = 0; l < LIMG; ++l) {
    float v = r[l] * r[l];
    #pragma unroll
    for (int sh = 32; sh > 0; sh >>= 1) v += __shfl_down(v, sh);
    if (lane == 0) ps[wid][l] = v;
  }
  __syncthreads();
  float q[LIMG];
  #pragma unroll
  for (int l = 0; l < LIMG; ++l) {
    float n = fmaxf(sqrtf(ps[0][l] + ps[1][l]), 1e-12f);
    q[l] = r[l] / n;
    qs[l][d] = q[l];
  }
  __syncthreads();
  if (d < 16) {
    int n = d >> 2, m = d & 3;
    float s = 0.f;
    for (int t = 0; t < CD; ++t) s = fmaf(qs[n][t], qs[m][t], s);
    dm[d] = s * 0.08838834764831843f;     // 1/sqrt(128)
  }
  __syncthreads();
  #pragma unroll
  for (int n = 0; n < LIMG; ++n) {
    float a0 = dm[n*4+0], a1 = dm[n*4+1], a2 = dm[n*4+2], a3 = dm[n*4+3];
    float mx = fmaxf(fmaxf(a0, a1), fmaxf(a2, a3));
    float e0 = expf(a0 - mx), e1 = expf(a1 - mx), e2 = expf(a2 - mx), e3 = expf(a3 - mx);
    float inv = 1.0f / (e0 + e1 + e2 + e3);
    float msg = (e0 * q[0] + e1 * q[1] + e2 * q[2] + e3 * q[3]) * inv;
    d2[(size_t)(n * CD + d) * KP + k] = 2.0f * q[n] + msg;
  }
}

// ---------------- conv1d k=3 pad=1 + relu ----------------
__global__ __launch_bounds__(256) void k_proj(const float* __restrict__ d2, const float* __restrict__ pw,
                                              const float* __restrict__ pb, float* __restrict__ d3) {
  int b = blockIdx.x;
  int l = b >> 7, o = b & 127;
  int k = threadIdx.x;
  float acc = pb[o];
  for (int c = 0; c < CD; ++c) {
    const float* row = d2 + (size_t)(l * CD + c) * KP;
    float xm = (k > 0)      ? row[k - 1] : 0.f;
    float x0 = row[k];
    float xp = (k < KP - 1) ? row[k + 1] : 0.f;
    const float* w = pw + (size_t)(o * CD + c) * 3;
    acc = fmaf(w[0], xm, acc);
    acc = fmaf(w[1], x0, acc);
    acc = fmaf(w[2], xp, acc);
  }
  d3[(size_t)(l * CD + o) * KP + k] = fmaxf(acc, 0.f);
}

// ---------------- fused: conv1d k=1 + stable descending argsort + gather ----------------
__global__ __launch_bounds__(256) void k_projsort(const float* __restrict__ d3,
                                                  const float* __restrict__ psw,
                                                  const float* __restrict__ psb,
                                                  float* __restrict__ d4) {
  int b = blockIdx.x;
  int l = b >> 7, o = b & 127;
  int k = threadIdx.x;
  __shared__ float srow[KP];
  float acc = psb[o];
  for (int c = 0; c < CD; ++c)
    acc = fmaf(psw[o * CD + c], d3[(size_t)(l * CD + c) * KP + k], acc);
  srow[k] = acc;
  __syncthreads();
  int rank = 0;
  for (int m = 0; m < KP; ++m) {
    float sm = srow[m];
    rank += (sm > acc || (sm == acc && m < k)) ? 1 : 0;
  }
  int base = (l * CD + o) * KP;
  d4[base + rank] = d3[base + k];
}

// ---------------- fused: final conv1d (128->3) + min|diff| -> theta ----------------
__global__ __launch_bounds__(1024) void k_finaltheta(const float* __restrict__ d4,
                                                     const float* __restrict__ fw,
                                                     const float* __restrict__ fb,
                                                     float* __restrict__ theta) {
  __shared__ float accs[LIMG][KP][3];
  __shared__ float res[LIMG][3];
  int tid = threadIdx.x;
  int l = tid >> 8, k = tid & 255;
  float a0 = fb[0], a1 = fb[1], a2 = fb[2];
  const float* dl = d4 + (size_t)l * CD * KP + k;
  for (int c = 0; c < CD; ++c) {
    float v = dl[(size_t)c * KP];
    a0 = fmaf(fw[0 * CD + c], v, a0);
    a1 = fmaf(fw[1 * CD + c], v, a1);
    a2 = fmaf(fw[2 * CD + c], v, a2);
  }
  accs[l][k][0] = a0; accs[l][k][1] = a1; accs[l][k][2] = a2;
  __syncthreads();
  int wid = tid >> 6, lane = tid & 63;
  if (wid < 12) {
    int rl = wid / 3, ro = wid - rl * 3;
    float m = 3.402823466e38f;
    #pragma unroll
    for (int t = 0; t < 4; ++t) {
      int kk = lane + 64 * t;
      m = fminf(m, fabsf(accs[rl][kk][ro] - accs[0][kk][ro]));
    }
    #pragma unroll
    for (int s = 32; s > 0; s >>= 1) m = fminf(m, __shfl_down(m, s));
    if (lane == 0) res[rl][ro] = m;
  }
  __syncthreads();
  if (tid == 0) {
    for (int l2 = 0; l2 < LIMG; ++l2) {
      float tx = res[l2][0], ty = res[l2][1], th = res[l2][2];
      float cth = cosf(th), sth = sinf(th);
      theta[l2*6+0] = cth;  theta[l2*6+1] = -sth; theta[l2*6+2] = tx;
      theta[l2*6+3] = sth;  theta[l2*6+4] = cth;  theta[l2*6+5] = ty;
    }
  }
}

// ---------------- bilinear grid sample: 8 channels per thread ----------------
__global__ __launch_bounds__(256) void k_sample(const float* __restrict__ feats,
                                                const float* __restrict__ theta,
                                                float* __restrict__ out) {
  int b = blockIdx.x;
  int pb = b & 127;
  int cg = (b >> 7) & 31;
  int l  = b >> 12;
  int pi = pb * 256 + threadIdx.x;
  int x = pi & 255, y = pi >> 8;
  const float* t = theta + l * 6;
  float X = (x + 0.5f) * (2.0f / WW) - 1.0f;
  float Y = (y + 0.5f) * (2.0f / HH) - 1.0f;
  float gx = t[0] * X + t[1] * Y + t[2];
  float gy = t[3] * X + t[4] * Y + t[5];
  float ix = ((gx + 1.0f) * WW - 1.0f) * 0.5f;
  float iy = ((gy + 1.0f) * HH - 1.0f) * 0.5f;
  float x0 = floorf(ix), y0 = floorf(iy);
  float x1 = x0 + 1.0f,  y1 = y0 + 1.0f;
  float wa = (x1 - ix) * (y1 - iy);
  float wb = (ix - x0) * (y1 - iy);
  float wc = (x1 - ix) * (iy - y0);
  float wd = (ix - x0) * (iy - y0);
  bool vx0 = (x0 >= 0.f) && (x0 <= (float)(WW-1));
  bool vx1 = (x1 >= 0.f) && (x1 <= (float)(WW-1));
  bool vy0 = (y0 >= 0.f) && (y0 <= (float)(HH-1));
  bool vy1 = (y1 >= 0.f) && (y1 <= (float)(HH-1));
  wa = (vx0 && vy0) ? wa : 0.f;
  wb = (vx1 && vy0) ? wb : 0.f;
  wc = (vx0 && vy1) ? wc : 0.f;
  wd = (vx1 && vy1) ? wd : 0.f;
  int xc0 = (int)fminf(fmaxf(x0, 0.f), (float)(WW-1));
  int xc1 = (int)fminf(fmaxf(x1, 0.f), (float)(WW-1));
  int yc0 = (int)fminf(fmaxf(y0, 0.f), (float)(HH-1));
  int yc1 = (int)fminf(fmaxf(y1, 0.f), (float)(HH-1));
  int o00 = yc0 * WW + xc0;
  int o10 = yc0 * WW + xc1;
  int o01 = yc1 * WW + xc0;
  int o11 = yc1 * WW + xc1;
  const float* img = feats + (size_t)(l * CIN + cg * 8) * HW;
  float* op = out + (size_t)(l * CIN + cg * 8) * HW + pi;
  #pragma unroll
  for (int i = 0; i < 8; ++i) {
    const float* im = img + (size_t)i * HW;
    float acc = im[o00] * wa + im[o10] * wb + im[o01] * wc + im[o11] * wd;
    op[(size_t)i * HW] = acc;
  }
}

extern "C" void kernel_launch(void* const* d_in, const int* in_sizes, int n_in,
                              void* d_out, int out_size, void* d_ws, size_t ws_size,
                              hipStream_t stream) {
  const float* feats = (const float*)d_in[0];
  const float* wS    = (const float*)d_in[1];
  const float* bS    = (const float*)d_in[2];
  const float* wD    = (const float*)d_in[3];
  const float* bD    = (const float*)d_in[4];
  const float* pw    = (const float*)d_in[5];
  const float* pb    = (const float*)d_in[6];
  const float* psw   = (const float*)d_in[7];
  const float* psb   = (const float*)d_in[8];
  const float* fw    = (const float*)d_in[9];
  const float* fb    = (const float*)d_in[10];
  float* out = (float*)d_out;

  char* base = (char*)d_ws;
  size_t off = 0;
  auto alloc = [&](size_t bytes) -> void* {
    void* p = base + off;
    off = (off + bytes + 255) & ~(size_t)255;
    return p;
  };
  float* g      = (float*)alloc((size_t)NSP * 9 * LHW * sizeof(float));
  float* scores = (float*)alloc((size_t)LHW * 4);
  float* maskA  = (float*)alloc((size_t)LHW * 4);
  float* maskB  = (float*)alloc((size_t)LHW * 4);
  float* d2     = (float*)alloc((size_t)LHW * 4);
  float* d3     = (float*)alloc((size_t)LHW * 4);
  float* d4     = (float*)alloc((size_t)LHW * 4);
  float* wT     = (float*)alloc((size_t)CIN * 9 * CD * 4);
  float* pacc   = (float*)alloc((size_t)4 * LIMG * KP * CD * 4);
  float* theta  = (float*)alloc(24 * 4);
  float* csc    = (float*)alloc((size_t)LIMG * CAP * 4);
  int*   cidx   = (int*)  alloc((size_t)LIMG * CAP * 4);
  int*   cnt    = (int*)  alloc(64);
  int*   sel    = (int*)  alloc((size_t)LIMG * KP * 4);

  const int WT_BLOCKS = (CD * CIN * 9 + 255) / 256;   // 1152
  k_chanred<<<1024 + WT_BLOCKS, 256, 0, stream>>>(feats, wS, g, wD, wT, cnt);
  k_scores<<<512, 256, 0, stream>>>(g, bS, scores);
  k_nms01<<<128, 256, 0, stream>>>(scores, maskA);
  k_nms2<<<128, 256, 0, stream>>>(maskA, scores, maskB, cnt, cidx, csc);
  k_rankfill<<<32, 256, 0, stream>>>(cnt, cidx, csc, maskB, sel);
  k_desc1<<<256, 256, 0, stream>>>(feats, wT, sel, pacc);
  k_desc2attn<<<256, 128, 0, stream>>>(pacc, bD, d2);
  k_proj<<<512, 256, 0, stream>>>(d2, pw, pb, d3);
  k_projsort<<<512, 256, 0, stream>>>(d3, psw, psb, d4);
  k_finaltheta<<<1, 1024, 0, stream>>>(d4, fw, fb, theta);
  k_sample<<<16384, 256, 0, stream>>>(feats, theta, out);
}